// Round 14
// baseline (4350.978 us; speedup 1.0000x reference)
//
#include <hip/hip_runtime.h>

// ---------------- types / helpers ----------------
typedef unsigned short u16;
typedef __bf16 bf16x8 __attribute__((ext_vector_type(8)));
typedef float f32x4 __attribute__((ext_vector_type(4)));
typedef u16 u16x8 __attribute__((ext_vector_type(8)));
typedef unsigned u32x2 __attribute__((ext_vector_type(2)));

static_assert(sizeof(bf16x8) == 16, "bf16x8 must be 16B");

#define DEV static __device__ __forceinline__

DEV u16 f2bf(float f) {
  unsigned u = __float_as_uint(f);
  u += 0x7FFFu + ((u >> 16) & 1u);  // RNE
  return (u16)(u >> 16);
}
DEV float bf2f(u16 h) { return __uint_as_float(((unsigned)h) << 16); }
DEV f32x4 mfma16(bf16x8 a, bf16x8 b, f32x4 c) {
  return __builtin_amdgcn_mfma_f32_16x16x32_bf16(a, b, c, 0, 0, 0);
}
DEV bf16x8 ldfrag(const u16* p) { return *reinterpret_cast<const bf16x8*>(p); }
DEV float sigf(float x) { return 1.0f / (1.0f + __expf(-x)); }
DEV bf16x8 asbf(f32x4 v) { union { f32x4 f; bf16x8 h; } u; u.f = v; return u.h; }
DEV void gld16(const void* g, void* l) {
  __builtin_amdgcn_global_load_lds((const __attribute__((address_space(1))) void*)g,
                                   (__attribute__((address_space(3))) void*)l, 16, 0, 0);
}

// ---- coherent (MALL-level, cross-XCD) access helpers ----
DEV void ld_a16_coh(const void* p0, const void* p1,
                    f32x4& a0, f32x4& a1, f32x4& a2, f32x4& a3,
                    f32x4& a4, f32x4& a5, f32x4& a6, f32x4& a7,
                    f32x4& b0, f32x4& b1, f32x4& b2, f32x4& b3,
                    f32x4& b4, f32x4& b5, f32x4& b6, f32x4& b7) {
  asm volatile(
      "global_load_dwordx4 %0, %16, off sc0 sc1\n\t"
      "global_load_dwordx4 %1, %16, off offset:64 sc0 sc1\n\t"
      "global_load_dwordx4 %2, %16, off offset:128 sc0 sc1\n\t"
      "global_load_dwordx4 %3, %16, off offset:192 sc0 sc1\n\t"
      "global_load_dwordx4 %4, %16, off offset:256 sc0 sc1\n\t"
      "global_load_dwordx4 %5, %16, off offset:320 sc0 sc1\n\t"
      "global_load_dwordx4 %6, %16, off offset:384 sc0 sc1\n\t"
      "global_load_dwordx4 %7, %16, off offset:448 sc0 sc1\n\t"
      "global_load_dwordx4 %8, %17, off sc0 sc1\n\t"
      "global_load_dwordx4 %9, %17, off offset:64 sc0 sc1\n\t"
      "global_load_dwordx4 %10, %17, off offset:128 sc0 sc1\n\t"
      "global_load_dwordx4 %11, %17, off offset:192 sc0 sc1\n\t"
      "global_load_dwordx4 %12, %17, off offset:256 sc0 sc1\n\t"
      "global_load_dwordx4 %13, %17, off offset:320 sc0 sc1\n\t"
      "global_load_dwordx4 %14, %17, off offset:384 sc0 sc1\n\t"
      "global_load_dwordx4 %15, %17, off offset:448 sc0 sc1\n\t"
      "s_waitcnt vmcnt(0)"
      : "=&v"(a0), "=&v"(a1), "=&v"(a2), "=&v"(a3), "=&v"(a4), "=&v"(a5), "=&v"(a6), "=&v"(a7),
        "=&v"(b0), "=&v"(b1), "=&v"(b2), "=&v"(b3), "=&v"(b4), "=&v"(b5), "=&v"(b6), "=&v"(b7)
      : "v"(p0), "v"(p1)
      : "memory");
}
// same, but no trailing waitcnt (issue-only; a later ld_a16_coh's vmcnt(0) covers these)
DEV void ld_a16_coh_nw(const void* p0, const void* p1,
                       f32x4& a0, f32x4& a1, f32x4& a2, f32x4& a3,
                       f32x4& a4, f32x4& a5, f32x4& a6, f32x4& a7,
                       f32x4& b0, f32x4& b1, f32x4& b2, f32x4& b3,
                       f32x4& b4, f32x4& b5, f32x4& b6, f32x4& b7) {
  asm volatile(
      "global_load_dwordx4 %0, %16, off sc0 sc1\n\t"
      "global_load_dwordx4 %1, %16, off offset:64 sc0 sc1\n\t"
      "global_load_dwordx4 %2, %16, off offset:128 sc0 sc1\n\t"
      "global_load_dwordx4 %3, %16, off offset:192 sc0 sc1\n\t"
      "global_load_dwordx4 %4, %16, off offset:256 sc0 sc1\n\t"
      "global_load_dwordx4 %5, %16, off offset:320 sc0 sc1\n\t"
      "global_load_dwordx4 %6, %16, off offset:384 sc0 sc1\n\t"
      "global_load_dwordx4 %7, %16, off offset:448 sc0 sc1\n\t"
      "global_load_dwordx4 %8, %17, off sc0 sc1\n\t"
      "global_load_dwordx4 %9, %17, off offset:64 sc0 sc1\n\t"
      "global_load_dwordx4 %10, %17, off offset:128 sc0 sc1\n\t"
      "global_load_dwordx4 %11, %17, off offset:192 sc0 sc1\n\t"
      "global_load_dwordx4 %12, %17, off offset:256 sc0 sc1\n\t"
      "global_load_dwordx4 %13, %17, off offset:320 sc0 sc1\n\t"
      "global_load_dwordx4 %14, %17, off offset:384 sc0 sc1\n\t"
      "global_load_dwordx4 %15, %17, off offset:448 sc0 sc1"
      : "=&v"(a0), "=&v"(a1), "=&v"(a2), "=&v"(a3), "=&v"(a4), "=&v"(a5), "=&v"(a6), "=&v"(a7),
        "=&v"(b0), "=&v"(b1), "=&v"(b2), "=&v"(b3), "=&v"(b4), "=&v"(b5), "=&v"(b6), "=&v"(b7)
      : "v"(p0), "v"(p1)
      : "memory");
}
DEV f32x4 ld16_coh(const void* p) {
  f32x4 r;
  asm volatile("global_load_dwordx4 %0, %1, off sc0 sc1\n\ts_waitcnt vmcnt(0)"
               : "=&v"(r) : "v"(p) : "memory");
  return r;
}
DEV void ld2x16_coh(const void* p0, const void* p1, f32x4& a, f32x4& b) {
  asm volatile(
      "global_load_dwordx4 %0, %2, off sc0 sc1\n\t"
      "global_load_dwordx4 %1, %3, off sc0 sc1\n\t"
      "s_waitcnt vmcnt(0)"
      : "=&v"(a), "=&v"(b) : "v"(p0), "v"(p1) : "memory");
}
DEV void st32_coh(void* p, unsigned v) {
  asm volatile("global_store_dword %0, %1, off sc0 sc1" ::"v"(p), "v"(v) : "memory");
}
DEV void st8_coh(void* p, unsigned lo, unsigned hi) {
  u32x2 v; v[0] = lo; v[1] = hi;
  asm volatile("global_store_dwordx2 %0, %1, off sc0 sc1" ::"v"(p), "v"(v) : "memory");
}

// ---- store-based flag sync: one 64B line per producer block, wave-vectorized polls ----
DEV unsigned ldflag(const unsigned* p) {
  unsigned r;
  asm volatile("global_load_dword %0, %1, off sc0 sc1\n\ts_waitcnt vmcnt(0)"
               : "=&v"(r) : "v"(p) : "memory");
  return r;
}
DEV void poll128(const unsigned* fl, unsigned tgt) {  // 128 flags, stride 16 u32
  if (tgt == 0) return;
  if (threadIdx.x < 64) {
    const unsigned* p0 = fl + (size_t)threadIdx.x * 16;
    const unsigned* p1 = fl + (size_t)(threadIdx.x + 64) * 16;
    for (;;) {
      unsigned a, b;
      asm volatile(
          "global_load_dword %0, %2, off sc0 sc1\n\t"
          "global_load_dword %1, %3, off sc0 sc1\n\t"
          "s_waitcnt vmcnt(0)"
          : "=&v"(a), "=&v"(b) : "v"(p0), "v"(p1) : "memory");
      if (__all((a >= tgt) && (b >= tgt))) break;
      __builtin_amdgcn_s_sleep(1);
    }
  }
  __syncthreads();
}
DEV void poll32(const unsigned* fl, unsigned tgt) {  // 32 flags
  if (threadIdx.x < 64) {
    const unsigned* p0 = fl + (size_t)(threadIdx.x & 31) * 16;
    for (;;) {
      unsigned a = ldflag(p0);
      if (__all(a >= tgt)) break;
      __builtin_amdgcn_s_sleep(1);
    }
  }
  __syncthreads();
}
DEV void pollAB(const unsigned* f0, unsigned t0, const unsigned* f1, unsigned t1) {
  const bool n0 = t0 > 0, n1 = t1 > 0;
  if ((n0 || n1) && threadIdx.x < 64) {
    const unsigned* q0 = f0 + (size_t)threadIdx.x * 16;
    const unsigned* q1 = f0 + (size_t)(threadIdx.x + 64) * 16;
    const unsigned* q2 = f1 + (size_t)threadIdx.x * 16;
    const unsigned* q3 = f1 + (size_t)(threadIdx.x + 64) * 16;
    for (;;) {
      unsigned a, b, c, d;
      asm volatile(
          "global_load_dword %0, %4, off sc0 sc1\n\t"
          "global_load_dword %1, %5, off sc0 sc1\n\t"
          "global_load_dword %2, %6, off sc0 sc1\n\t"
          "global_load_dword %3, %7, off sc0 sc1\n\t"
          "s_waitcnt vmcnt(0)"
          : "=&v"(a), "=&v"(b), "=&v"(c), "=&v"(d)
          : "v"(q0), "v"(q1), "v"(q2), "v"(q3) : "memory");
      bool ok = true;
      if (n0) ok = ok && (a >= t0) && (b >= t0);
      if (n1) ok = ok && (c >= t1) && (d >= t1);
      if (__all(ok)) break;
      __builtin_amdgcn_s_sleep(1);
    }
  }
  __syncthreads();
}
DEV void setflag(unsigned* f, unsigned v) {  // drain all waves' stores, then publish
  asm volatile("s_waitcnt vmcnt(0)" ::: "memory");
  __syncthreads();
  if (threadIdx.x == 0) st32_coh(f, v);
}

// dims
#define Bn 32
#define Sn 128
#define Td 127
#define En 512
#define Hn 1024
#define G4 4096
#define Vn 32000
#define NSTG 63  // enc rows staged in scorer LDS

// ---------------- f32 -> bf16 convert ----------------
typedef u16 u16x8b __attribute__((ext_vector_type(8)));
__global__ __launch_bounds__(256) void cvt_bf16_kernel(const float* __restrict__ in,
                                                       u16* __restrict__ out, int n8) {
  int gid = blockIdx.x * 256 + threadIdx.x;
  if (gid >= n8) return;
  const float4* ip = (const float4*)in + gid * 2;
  float4 x = ip[0], y = ip[1];
  u16x8b o;
  o[0] = f2bf(x.x); o[1] = f2bf(x.y); o[2] = f2bf(x.z); o[3] = f2bf(x.w);
  o[4] = f2bf(y.x); o[5] = f2bf(y.y); o[6] = f2bf(y.z); o[7] = f2bf(y.w);
  ((u16x8b*)out)[gid] = o;
}

// ---------------- embedding gather ----------------
__global__ __launch_bounds__(256) void gather_embed_kernel(const int* __restrict__ idx, int ldidx,
                                                           const float* __restrict__ embed,
                                                           u16* __restrict__ outA, int nrows) {
  int gid = blockIdx.x * 256 + threadIdx.x;
  int total = nrows * (En / 8);
  if (gid >= total) return;
  int r = gid / (En / 8);
  int ck = gid % (En / 8);
  int tcol = r / Bn, b = r % Bn;
  int tok = idx[b * ldidx + tcol];
  const float4* src = (const float4*)(embed + (size_t)tok * En + ck * 8);
  float4 x = src[0], y = src[1];
  u16x8b o;
  o[0] = f2bf(x.x); o[1] = f2bf(x.y); o[2] = f2bf(x.z); o[3] = f2bf(x.w);
  o[4] = f2bf(y.x); o[5] = f2bf(y.y); o[6] = f2bf(y.z); o[7] = f2bf(y.w);
  *(u16x8b*)(outA + (size_t)r * En + ck * 8) = o;
}

// ---------------- tiled GEMM (128x128, BK=32, global_load_lds) ----------------
// mode0: C row-major f32 (+bias0+bias1). mode1: fc epilogue (out[(b*Td+t)*Vn+n]).
__global__ __launch_bounds__(256) void gemm_tile_kernel(const u16* __restrict__ A, int lda,
                                                        const u16* __restrict__ W, int ldw,
                                                        const float* __restrict__ bias0,
                                                        const float* __restrict__ bias1,
                                                        float* __restrict__ Cout, int ldc,
                                                        int Mtiles, int K, int mode) {
  __shared__ u16 Asb[128 * 32];
  __shared__ u16 Bsb[128 * 32];
  int nwg = gridDim.x;
  int cpx = nwg >> 3;
  int bid = ((int)blockIdx.x & 7) * cpx + ((int)blockIdx.x >> 3);
  int mt = bid % Mtiles, nt = bid / Mtiles;
  int tid = threadIdx.x;
  int wave = tid >> 6, lane = tid & 63;
  int lrow = lane & 15, kgrp = lane >> 4;
  int wr = wave >> 1, wc = wave & 1;
  int e0 = wave * 1024 + lane * 8;
  int r0 = e0 >> 5, c0 = e0 & 31;
  int r1 = r0 + 16;
  const u16* Ab = A + (size_t)(mt * 128) * lda;
  const u16* Wb = W + (size_t)(nt * 128) * ldw;
  u16* AsW = Asb + wave * 1024;
  u16* BsW = Bsb + wave * 1024;
  f32x4 acc[4][4] = {};
  for (int k0 = 0; k0 < K; k0 += 32) {
    gld16(Ab + (size_t)r0 * lda + k0 + c0, AsW);
    gld16(Ab + (size_t)r1 * lda + k0 + c0, AsW + 512);
    gld16(Wb + (size_t)r0 * ldw + k0 + c0, BsW);
    gld16(Wb + (size_t)r1 * ldw + k0 + c0, BsW + 512);
    __syncthreads();
    bf16x8 af[4], bfr[4];
#pragma unroll
    for (int i = 0; i < 4; ++i) af[i] = ldfrag(Asb + (wr * 64 + i * 16 + lrow) * 32 + kgrp * 8);
#pragma unroll
    for (int i = 0; i < 4; ++i) bfr[i] = ldfrag(Bsb + (wc * 64 + i * 16 + lrow) * 32 + kgrp * 8);
#pragma unroll
    for (int i = 0; i < 4; ++i)
#pragma unroll
      for (int j = 0; j < 4; ++j) acc[i][j] = mfma16(af[i], bfr[j], acc[i][j]);
    __syncthreads();
  }
  if (mode == 0) {
#pragma unroll
    for (int i = 0; i < 4; ++i) {
      int m = mt * 128 + wr * 64 + i * 16 + kgrp * 4;
#pragma unroll
      for (int j = 0; j < 4; ++j) {
        int n = nt * 128 + wc * 64 + j * 16 + lrow;
        float bb = (bias0 ? bias0[n] : 0.f) + (bias1 ? bias1[n] : 0.f);
#pragma unroll
        for (int r = 0; r < 4; ++r) Cout[(size_t)(m + r) * ldc + n] = acc[i][j][r] + bb;
      }
    }
  } else {
#pragma unroll
    for (int i = 0; i < 4; ++i) {
      int m = mt * 128 + wr * 64 + i * 16 + kgrp * 4;
#pragma unroll
      for (int j = 0; j < 4; ++j) {
        int n = nt * 128 + wc * 64 + j * 16 + lrow;
        float bb = bias0[n];
#pragma unroll
        for (int r = 0; r < 4; ++r) {
          int mm = m + r;
          if (mm < Td * Bn) {
            int tt = mm >> 5, b = mm & 31;
            Cout[((size_t)b * Td + tt) * Vn + n] = acc[i][j][r] + bb;
          }
        }
      }
    }
  }
}

// ---------------- persistent building blocks ----------------
DEV void mm8b(const u16* __restrict__ A0, const char* __restrict__ Wl, int pitchB,
              int kByteBase, int lane, f32x4 acc[2][2]) {
  const int lrow = lane & 15, kgrp = lane >> 4;
  const char* wr0 = Wl + (size_t)lrow * pitchB;
  const char* wr1 = wr0 + (size_t)16 * pitchB;
  const int sw = (lrow & 7) << 4;
  f32x4 s0, s1, s2, s3, s4, s5, s6, s7, u0, u1, u2, u3, u4, u5, u6, u7;
  ld_a16_coh(A0 + (size_t)lrow * 1024 + kgrp * 8, A0 + (size_t)(16 + lrow) * 1024 + kgrp * 8,
             s0, s1, s2, s3, s4, s5, s6, s7, u0, u1, u2, u3, u4, u5, u6, u7);
#define KS(T, U, J, KB)                                                \
  {                                                                    \
    bf16x8 a = asbf(T);                                                \
    int kb = (KB) + (J) * 64 + kgrp * 16;                              \
    bf16x8 w0 = *(const bf16x8*)(wr0 + (size_t)(kb ^ sw));             \
    bf16x8 w1 = *(const bf16x8*)(wr1 + (size_t)(kb ^ sw));             \
    acc[0][0] = mfma16(a, w0, acc[0][0]);                              \
    acc[0][1] = mfma16(a, w1, acc[0][1]);                              \
    bf16x8 cc = asbf(U);                                               \
    acc[1][0] = mfma16(cc, w0, acc[1][0]);                             \
    acc[1][1] = mfma16(cc, w1, acc[1][1]);                             \
  }
  KS(s0, u0, 0, kByteBase) KS(s1, u1, 1, kByteBase) KS(s2, u2, 2, kByteBase)
  KS(s3, u3, 3, kByteBase) KS(s4, u4, 4, kByteBase) KS(s5, u5, 5, kByteBase)
  KS(s6, u6, 6, kByteBase) KS(s7, u7, 7, kByteBase)
}

// paired variant: covers 512 K-elements (two 256-elem batches) with ONE vmcnt wait.
DEV void mm8b_pair(const u16* __restrict__ A0, const char* __restrict__ Wl, int pitchB,
                   int kByteBase, int lane, f32x4 acc[2][2]) {
  const int lrow = lane & 15, kgrp = lane >> 4;
  const char* wr0 = Wl + (size_t)lrow * pitchB;
  const char* wr1 = wr0 + (size_t)16 * pitchB;
  const int sw = (lrow & 7) << 4;
  f32x4 s0, s1, s2, s3, s4, s5, s6, s7, u0, u1, u2, u3, u4, u5, u6, u7;
  f32x4 t0, t1, t2, t3, t4, t5, t6, t7, v0, v1, v2, v3, v4, v5, v6, v7;
  ld_a16_coh_nw(A0 + (size_t)lrow * 1024 + kgrp * 8, A0 + (size_t)(16 + lrow) * 1024 + kgrp * 8,
                s0, s1, s2, s3, s4, s5, s6, s7, u0, u1, u2, u3, u4, u5, u6, u7);
  ld_a16_coh(A0 + (size_t)lrow * 1024 + 256 + kgrp * 8,
             A0 + (size_t)(16 + lrow) * 1024 + 256 + kgrp * 8,
             t0, t1, t2, t3, t4, t5, t6, t7, v0, v1, v2, v3, v4, v5, v6, v7);
  __builtin_amdgcn_sched_barrier(0);  // rule #18: keep MFMAs below the vmcnt(0)
  KS(s0, u0, 0, kByteBase) KS(s1, u1, 1, kByteBase) KS(s2, u2, 2, kByteBase)
  KS(s3, u3, 3, kByteBase) KS(s4, u4, 4, kByteBase) KS(s5, u5, 5, kByteBase)
  KS(s6, u6, 6, kByteBase) KS(s7, u7, 7, kByteBase)
  KS(t0, v0, 0, kByteBase + 512) KS(t1, v1, 1, kByteBase + 512) KS(t2, v2, 2, kByteBase + 512)
  KS(t3, v3, 3, kByteBase + 512) KS(t4, v4, 4, kByteBase + 512) KS(t5, v5, 5, kByteBase + 512)
  KS(t6, v6, 6, kByteBase + 512) KS(t7, v7, 7, kByteBase + 512)
}

DEV void dump_acc(float* red, f32x4 acc[2][2], int wave, int lane) {
  int lrow = lane & 15, kgrp = lane >> 4;
#pragma unroll
  for (int m = 0; m < 2; ++m)
#pragma unroll
    for (int n = 0; n < 2; ++n)
#pragma unroll
      for (int r = 0; r < 4; ++r)
        red[((((wave * 2 + m) * 2 + n) * 16) + kgrp * 4 + r) * 16 + lrow] = acc[m][n][r];
}
DEV float rsum(const float* red, int m, int n, int rw, int l) {
  float s = 0.f;
#pragma unroll
  for (int w = 0; w < 4; ++w) s += red[((((w * 2 + m) * 2 + n) * 16) + rw) * 16 + l];
  return s;
}
DEV float lstm_apply(const float gs[4], float* c_reg) {
  float ig = sigf(gs[0]), fg = sigf(gs[1]), gg = tanhf(gs[2]), og = sigf(gs[3]);
  float cn = fg * (*c_reg) + ig * gg;
  *c_reg = cn;
  return og * tanhf(cn);
}

// ---------------- persistent encoder (round-13, unchanged) ----------------
__global__ __launch_bounds__(256, 1) void enc_persist8(
    const float* __restrict__ premix, const u16* __restrict__ Whh0, const u16* __restrict__ Wih1,
    const u16* __restrict__ Whh1, const float* __restrict__ bih1, const float* __restrict__ bhh1,
    u16* __restrict__ h0ring, u16* __restrict__ h1ring, float* __restrict__ c1_out,
    u16* __restrict__ enc_b, unsigned* __restrict__ f0, unsigned* __restrict__ f1) {
  extern __shared__ char lds[];
  float* red = (float*)(lds + 131072);
  const int tid = threadIdx.x, wave = tid >> 6, lane = tid & 63;
  const int blk = blockIdx.x;
  const bool l1 = blk >= 128;
  const int base = (blk & 127) * 8;
  if (!l1) {
    for (int i = tid; i < 4096; i += 256) {
      int c = i >> 7;
      int kb = (i & 127) << 4;
      int row = (c >> 3) * Hn + base + (c & 7);
      f32x4 v = *(const f32x4*)(Whh0 + (size_t)row * Hn + (kb >> 1));
      *(f32x4*)(lds + c * 2048 + (kb ^ ((c & 7) << 4))) = v;
    }
  } else {
    for (int i = tid; i < 8192; i += 256) {
      int c = i >> 8;
      int kb = (i & 255) << 4;
      int row = (c >> 3) * Hn + base + (c & 7);
      const u16* src = (kb < 2048) ? (Wih1 + (size_t)row * Hn + (kb >> 1))
                                   : (Whh1 + (size_t)row * Hn + ((kb - 2048) >> 1));
      f32x4 v = *(const f32x4*)src;
      *(f32x4*)(lds + c * 4096 + (kb ^ ((c & 7) << 4))) = v;
    }
  }
  const int b_ = tid >> 3, hc = tid & 7;
  const int m = b_ >> 4, rw = b_ & 15;
  const size_t off = (size_t)b_ * Hn + base + hc;
  float c_reg = 0.f;
  __syncthreads();
  if (!l1) {
    for (int i = 0; i < Sn; ++i) {
      pollAB(f0, (unsigned)i, f1, (i >= 3) ? (unsigned)(i - 2) : 0u);
      const u16* hin = h0ring + (size_t)(i & 3) * (Bn * Hn);
      const float* pmr = premix + (size_t)i * (Bn * G4) + (size_t)b_ * G4 + base + hc;
      float pmv[4];
#pragma unroll
      for (int g = 0; g < 4; ++g) pmv[g] = pmr[(size_t)g * Hn];
      f32x4 acc[2][2] = {};
      mm8b(hin + wave * 256, lds, 2048, wave * 512, lane, acc);
      dump_acc(red, acc, wave, lane);
      __syncthreads();
      float gs[4];
#pragma unroll
      for (int g = 0; g < 4; ++g) {
        int c = g * 8 + hc;
        gs[g] = rsum(red, m, c >> 4, rw, c & 15) + pmv[g];
      }
      float hn = lstm_apply(gs, &c_reg);
      u16 mine = f2bf(hn);
      unsigned nb = (unsigned)(u16)__shfl_xor((int)mine, 1);
      if (!(tid & 1))
        st32_coh(h0ring + (size_t)((i + 1) & 3) * (Bn * Hn) + off,
                 ((unsigned)mine) | (nb << 16));
      setflag(f0 + blk * 16, (unsigned)(i + 1));
    }
  } else {
    float badd[4];
#pragma unroll
    for (int g = 0; g < 4; ++g) badd[g] = bih1[g * Hn + base + hc] + bhh1[g * Hn + base + hc];
    for (int j = 0; j < Sn; ++j) {
      pollAB(f0, (unsigned)(j + 1), f1, (unsigned)j);
      const u16* h0r = h0ring + (size_t)((j + 1) & 3) * (Bn * Hn);  // h0(j)
      const u16* h1r = h1ring + (size_t)(j & 1) * (Bn * Hn);        // h1(j-1)
      const u16* srcp = (wave < 2) ? h0r : h1r;
      int ko = (wave & 1) * 512;
      f32x4 acc[2][2] = {};
      mm8b_pair(srcp + ko, lds, 4096, wave * 1024, lane, acc);
      dump_acc(red, acc, wave, lane);
      __syncthreads();
      float gs[4];
#pragma unroll
      for (int g = 0; g < 4; ++g) {
        int c = g * 8 + hc;
        gs[g] = rsum(red, m, c >> 4, rw, c & 15) + badd[g];
      }
      float hn = lstm_apply(gs, &c_reg);
      u16 mine = f2bf(hn);
      unsigned nb = (unsigned)(u16)__shfl_xor((int)mine, 1);
      unsigned packed = ((unsigned)mine) | (nb << 16);
      if (!(tid & 1)) {
        st32_coh(h1ring + (size_t)((j + 1) & 1) * (Bn * Hn) + off, packed);
        *(unsigned*)(enc_b + (size_t)j * (Bn * Hn) + off) = packed;  // plain: later kernels
      }
      if (j == Sn - 1) c1_out[off] = c_reg;
      setflag(f1 + (blk - 128) * 16, (unsigned)(j + 1));
    }
  }
}

// ---------------- persistent decoder v11: LDS-staged enc rows in scorer ----------------
// blk<128 gate: unchanged round-13. blk in [128,160) scorer b:
//   startup: stage enc rows s=0..NSTG-1 (129 KB) into LDS.
//   per iter: poll fg>=t -> h direct coherent -> pass1 (LDS/L2 mix, 2-shfl pre-reduce)
//   -> 8-add reduce -> softmax -> pass2 (LDS/L2 mix) -> combine -> fa[b]=t+1.
// Lane column ownership: cols {lane*8+k} and {512+lane*8+k}, k=0..7 (conflict-free LDS reads).
__global__ __launch_bounds__(256, 1) void dec_persist11(
    const float* __restrict__ premix, const u16* __restrict__ Wctx, const u16* __restrict__ Whh,
    const float* __restrict__ c_init, u16* __restrict__ hbuf /*2 slots*/,
    const u16* __restrict__ enc_b, u16* __restrict__ ctxb, u16* __restrict__ hs_dec,
    unsigned* __restrict__ fg, unsigned* __restrict__ fa) {
  extern __shared__ char lds[];
  const int tid = threadIdx.x, wave = tid >> 6, lane = tid & 63;
  const int blk = blockIdx.x;
  if (blk < 128) {
    float* red = (float*)(lds + 131072);  // 16 KB; total 147456 B dynamic LDS
    const int cg = blk, base = cg * 8;
    for (int i = tid; i < 8192; i += 256) {
      int c = i >> 8;
      int kb = (i & 255) << 4;
      int row = (c >> 3) * Hn + base + (c & 7);
      const u16* src = (kb < 2048) ? (Whh + (size_t)row * Hn + (kb >> 1))
                                   : (Wctx + (size_t)row * 1536 + ((kb - 2048) >> 1));
      f32x4 v = *(const f32x4*)src;
      *(f32x4*)(lds + c * 4096 + (kb ^ ((c & 7) << 4))) = v;
    }
    const int b_ = tid >> 3, hc = tid & 7;
    const int m = b_ >> 4, rw = b_ & 15;
    const size_t off = (size_t)b_ * Hn + base + hc;
    float c_reg = c_init[off];
    __syncthreads();
    for (int t = 0; t < Td; ++t) {
      poll128(fg, (unsigned)t);  // h(t) ready (t=0: preloaded h_last)
      const float* pmr = premix + (size_t)t * (Bn * G4) + (size_t)b_ * G4 + base + hc;
      float pmv[4];
#pragma unroll
      for (int g = 0; g < 4; ++g) pmv[g] = pmr[(size_t)g * Hn];
      f32x4 acc[2][2] = {};
      mm8b(hbuf + (size_t)(t & 1) * (Bn * Hn) + wave * 256, lds, 4096, wave * 512, lane, acc);
      poll32(fa, (unsigned)(t + 1));
      mm8b(ctxb + wave * 256, lds, 4096, 2048 + wave * 512, lane, acc);
      dump_acc(red, acc, wave, lane);
      __syncthreads();
      float gs[4];
#pragma unroll
      for (int g = 0; g < 4; ++g) {
        int c = g * 8 + hc;
        gs[g] = rsum(red, m, c >> 4, rw, c & 15) + pmv[g];
      }
      float hn = lstm_apply(gs, &c_reg);
      u16 mine = f2bf(hn);
      unsigned nb = (unsigned)(u16)__shfl_xor((int)mine, 1);
      unsigned packed = ((unsigned)mine) | (nb << 16);
      if (!(tid & 1)) {
        st32_coh(hbuf + (size_t)((t + 1) & 1) * (Bn * Hn) + off, packed);
        *(unsigned*)(hs_dec + (size_t)t * (Bn * Hn) + off) = packed;  // plain: fc kernel
      }
      setflag(fg + cg * 16, (unsigned)(t + 1));
    }
  } else {
    // ---------------- scorer for batch b ----------------
    u16* encS = (u16*)lds;                                     // NSTG rows x 2048 B
    float* scl = (float*)(lds + NSTG * 2048);                  // 512 B
    float* wsm = (float*)(lds + NSTG * 2048 + 512);            // 512 B
    float* scpart = (float*)(lds + NSTG * 2048 + 1024);        // [128][17] = 8704 B
    float(*cpart)[16][64] = (float(*)[16][64])(lds + NSTG * 2048 + 1024);  // 16 KB (overlay)
    const int b = blk - 128;
    // ---- stage enc rows 0..NSTG-1 into LDS (once) ----
    for (int c = tid; c < NSTG * 128; c += 256) {   // 16B chunks; 128 per row
      int s = c >> 7, k = c & 127;
      f32x4 v = *(const f32x4*)(enc_b + ((size_t)s * Bn + b) * Hn + k * 8);
      *(f32x4*)(encS + (size_t)s * 1024 + k * 8) = v;
    }
    __syncthreads();
    for (int t = 0; t < Td; ++t) {
      poll128(fg, (unsigned)t);
      const u16* hb = hbuf + (size_t)(t & 1) * (Bn * Hn) + (size_t)b * Hn;
      // h: lane owns cols lane*8..+8 and 512+lane*8..+8 (coherent, 1 wait)
      float hf[16];
      {
        union { f32x4 f[2]; u16 u[16]; } U;
        ld2x16_coh(hb + lane * 8, hb + 512 + lane * 8, U.f[0], U.f[1]);
#pragma unroll
        for (int k2 = 0; k2 < 16; ++k2) hf[k2] = bf2f(U.u[k2]);
      }
      // pass 1: partial dots; 2-shfl pre-reduce to 16 entries/score
      for (int i = 0; i < 32; ++i) {
        int s = wave * 32 + i;
        const u16* er = (s < NSTG) ? (encS + (size_t)s * 1024)
                                   : (enc_b + ((size_t)s * Bn + b) * Hn);
        u16x8 e0 = *(const u16x8*)(er + lane * 8);
        u16x8 e1 = *(const u16x8*)(er + 512 + lane * 8);
        float p2 = 0.f;
#pragma unroll
        for (int k2 = 0; k2 < 8; ++k2) p2 += bf2f(e0[k2]) * hf[k2] + bf2f(e1[k2]) * hf[8 + k2];
        p2 += __shfl_xor(p2, 1);
        p2 += __shfl_xor(p2, 2);
        if ((lane & 3) == 0) scpart[s * 17 + (lane >> 2)] = p2;
      }
      __syncthreads();
      // reduce: 2 threads/score, 8 adds each, 1 shfl combine
      {
        int s2 = tid >> 1, half = tid & 1;
        const float* pp = scpart + s2 * 17 + half * 8;
        float p = pp[0] + pp[1] + pp[2] + pp[3] + pp[4] + pp[5] + pp[6] + pp[7];
        p += __shfl_xor(p, 1);
        if (half == 0) scl[s2] = p;
      }
      __syncthreads();
      if (wave == 0) {
        float sa = scl[lane], sb = scl[64 + lane];
        float mx = fmaxf(sa, sb);
#pragma unroll
        for (int o2 = 32; o2; o2 >>= 1) mx = fmaxf(mx, __shfl_xor(mx, o2));
        float ea = __expf(sa - mx), eb = __expf(sb - mx);
        float ss = ea + eb;
#pragma unroll
        for (int o2 = 32; o2; o2 >>= 1) ss += __shfl_xor(ss, o2);
        float inv = 1.0f / ss;
        wsm[lane] = ea * inv;
        wsm[64 + lane] = eb * inv;
      }
      __syncthreads();
      // pass 2: weighted accumulation over lane's 16 cols
      float a0[16];
#pragma unroll
      for (int q = 0; q < 16; ++q) a0[q] = 0.f;
      for (int i = 0; i < 32; ++i) {
        int s = wave * 32 + i;
        float w = wsm[s];
        const u16* er = (s < NSTG) ? (encS + (size_t)s * 1024)
                                   : (enc_b + ((size_t)s * Bn + b) * Hn);
        u16x8 e0 = *(const u16x8*)(er + lane * 8);
        u16x8 e1 = *(const u16x8*)(er + 512 + lane * 8);
#pragma unroll
        for (int q = 0; q < 8; ++q) {
          a0[q] += w * bf2f(e0[q]);
          a0[8 + q] += w * bf2f(e1[q]);
        }
      }
#pragma unroll
      for (int q = 0; q < 16; ++q) cpart[wave][q][lane] = a0[q];
      __syncthreads();
      {
        unsigned pk[2];
#pragma unroll
        for (int h2 = 0; h2 < 2; ++h2) {
          float vv[2];
#pragma unroll
          for (int e2 = 0; e2 < 2; ++e2) {
            int j = tid * 4 + h2 * 2 + e2;
            int jj = (j < 512) ? j : (j - 512);
            int qq = ((j < 512) ? 0 : 8) + (jj & 7);
            int ll = jj >> 3;
            vv[e2] = cpart[0][qq][ll] + cpart[1][qq][ll] + cpart[2][qq][ll] + cpart[3][qq][ll];
          }
          pk[h2] = (unsigned)f2bf(vv[0]) | ((unsigned)f2bf(vv[1]) << 16);
        }
        st8_coh(ctxb + (size_t)b * Hn + tid * 4, pk[0], pk[1]);
      }
      setflag(fa + b * 16, (unsigned)(t + 1));
    }
  }
}

// ---------------- host ----------------
extern "C" void kernel_launch(void* const* d_in, const int* in_sizes, int n_in,
                              void* d_out, int out_size, void* d_ws, size_t ws_size,
                              hipStream_t stream) {
  const int* src = (const int*)d_in[0];
  const int* tgt = (const int*)d_in[1];
  const float* embed = (const float*)d_in[2];
  const float* Wih0 = (const float*)d_in[3];
  const float* Whh0 = (const float*)d_in[4];
  const float* bih0 = (const float*)d_in[5];
  const float* bhh0 = (const float*)d_in[6];
  const float* Wih1 = (const float*)d_in[7];
  const float* Whh1 = (const float*)d_in[8];
  const float* bih1 = (const float*)d_in[9];
  const float* bhh1 = (const float*)d_in[10];
  const float* dWih = (const float*)d_in[11];
  const float* dWhh = (const float*)d_in[12];
  const float* dbih = (const float*)d_in[13];
  const float* dbhh = (const float*)d_in[14];
  const float* fcW = (const float*)d_in[15];
  const float* fcb = (const float*)d_in[16];
  float* out = (float*)d_out;

  (void)hipFuncSetAttribute((const void*)enc_persist8,
                            hipFuncAttributeMaxDynamicSharedMemorySize, 147456);
  (void)hipFuncSetAttribute((const void*)dec_persist11,
                            hipFuncAttributeMaxDynamicSharedMemorySize, 147456);

  char* p = (char*)d_ws;
  auto alloc = [&](size_t bytes) {
    void* r = p;
    p += (bytes + 255) & ~(size_t)255;
    return r;
  };
  u16* Wih0_b = (u16*)alloc((size_t)G4 * En * 2);
  u16* Whh0_b = (u16*)alloc((size_t)G4 * Hn * 2);
  u16* Wih1_b = (u16*)alloc((size_t)G4 * Hn * 2);
  u16* Whh1_b = (u16*)alloc((size_t)G4 * Hn * 2);
  u16* dWih_b = (u16*)alloc((size_t)G4 * 1536 * 2);
  u16* dWhh_b = (u16*)alloc((size_t)G4 * Hn * 2);
  u16* fcW_b = (u16*)alloc((size_t)Vn * Hn * 2);
  u16* embA = (u16*)alloc((size_t)4096 * En * 2);
  float* premix = (float*)alloc((size_t)4096 * G4 * 4);  // reused: enc l0, then decoder
  u16* enc_b = (u16*)alloc((size_t)Sn * Bn * Hn * 2);
  u16* hs_dec = (u16*)alloc((size_t)4096 * Hn * 2);
  u16* h0ring = (u16*)alloc((size_t)4 * Bn * Hn * 2);
  u16* h1ring = (u16*)alloc((size_t)2 * Bn * Hn * 2);
  float* c1g = (float*)alloc((size_t)Bn * Hn * 4);
  u16* ctx_b = (u16*)alloc((size_t)Bn * Hn * 2);
  unsigned* counters = (unsigned*)alloc(65536);
  unsigned* flagsE0 = counters;          // 128 x 16 u32
  unsigned* flagsE1 = counters + 2048;
  unsigned* flagsDg = counters + 4096;   // 128 x 16 u32
  unsigned* flagsDa = counters + 6144;   // 32 x 16 u32

  auto cvt = [&](const float* in, u16* o, size_t n) {
    int n8 = (int)(n / 8);
    cvt_bf16_kernel<<<(n8 + 255) / 256, 256, 0, stream>>>(in, o, n8);
  };
  cvt(Wih0, Wih0_b, (size_t)G4 * En);
  cvt(Whh0, Whh0_b, (size_t)G4 * Hn);
  cvt(Wih1, Wih1_b, (size_t)G4 * Hn);
  cvt(Whh1, Whh1_b, (size_t)G4 * Hn);
  cvt(dWih, dWih_b, (size_t)G4 * 1536);
  cvt(dWhh, dWhh_b, (size_t)G4 * Hn);
  cvt(fcW, fcW_b, (size_t)Vn * Hn);

  // encoder premix (layer0 input projection for all t)
  {
    int total = 4096 * (En / 8);
    gather_embed_kernel<<<(total + 255) / 256, 256, 0, stream>>>(src, Sn, embed, embA, Sn * Bn);
    gemm_tile_kernel<<<32 * 32, 256, 0, stream>>>(embA, En, Wih0_b, En, bih0, bhh0, premix, G4,
                                                  32, En, 0);
  }
  (void)hipMemsetAsync(h0ring, 0, (size_t)4 * Bn * Hn * 2, stream);
  (void)hipMemsetAsync(h1ring, 0, (size_t)2 * Bn * Hn * 2, stream);
  (void)hipMemsetAsync(counters, 0, 65536, stream);
  (void)hipMemsetAsync(hs_dec + (size_t)(Td * Bn) * Hn, 0, (size_t)(4096 - Td * Bn) * Hn * 2,
                       stream);

  enc_persist8<<<256, 256, 147456, stream>>>(premix, Whh0_b, Wih1_b, Whh1_b, bih1, bhh1, h0ring,
                                             h1ring, c1g, enc_b, flagsE0, flagsE1);

  // decoder premix
  {
    int nrows = Td * Bn;
    int total = nrows * (En / 8);
    gather_embed_kernel<<<(total + 255) / 256, 256, 0, stream>>>(tgt, Sn, embed, embA, nrows);
    gemm_tile_kernel<<<32 * 32, 256, 0, stream>>>(embA, En, dWih_b, 1536, dbih, dbhh, premix, G4,
                                                  32, En, 0);
  }

  dec_persist11<<<160, 256, 147456, stream>>>(premix, dWih_b + 512, dWhh_b, c1g,
                                              h1ring /* slot0 = h_last */, enc_b, ctx_b, hs_dec,
                                              flagsDg, flagsDa);

  // batched fc: out = hs_dec @ fc_W^T + fc_b
  gemm_tile_kernel<<<32 * 250, 256, 0, stream>>>(hs_dec, Hn, fcW_b, Hn, fcb, nullptr, out, 0,
                                                 32, Hn, 1);
}

// Round 15
// 3209.200 us; speedup vs baseline: 1.3558x; 1.3558x over previous
//
#include <hip/hip_runtime.h>

// ---------------- types / helpers ----------------
typedef unsigned short u16;
typedef __bf16 bf16x8 __attribute__((ext_vector_type(8)));
typedef float f32x4 __attribute__((ext_vector_type(4)));
typedef u16 u16x8 __attribute__((ext_vector_type(8)));
typedef unsigned u32x2 __attribute__((ext_vector_type(2)));

static_assert(sizeof(bf16x8) == 16, "bf16x8 must be 16B");

#define DEV static __device__ __forceinline__

DEV u16 f2bf(float f) {
  unsigned u = __float_as_uint(f);
  u += 0x7FFFu + ((u >> 16) & 1u);  // RNE
  return (u16)(u >> 16);
}
DEV float bf2f(u16 h) { return __uint_as_float(((unsigned)h) << 16); }
DEV f32x4 mfma16(bf16x8 a, bf16x8 b, f32x4 c) {
  return __builtin_amdgcn_mfma_f32_16x16x32_bf16(a, b, c, 0, 0, 0);
}
DEV bf16x8 ldfrag(const u16* p) { return *reinterpret_cast<const bf16x8*>(p); }
DEV float sigf(float x) { return 1.0f / (1.0f + __expf(-x)); }
DEV bf16x8 asbf(f32x4 v) { union { f32x4 f; bf16x8 h; } u; u.f = v; return u.h; }
DEV void gld16(const void* g, void* l) {
  __builtin_amdgcn_global_load_lds((const __attribute__((address_space(1))) void*)g,
                                   (__attribute__((address_space(3))) void*)l, 16, 0, 0);
}

// ---- coherent (MALL-level, cross-XCD) access helpers ----
DEV void ld_a16_coh(const void* p0, const void* p1,
                    f32x4& a0, f32x4& a1, f32x4& a2, f32x4& a3,
                    f32x4& a4, f32x4& a5, f32x4& a6, f32x4& a7,
                    f32x4& b0, f32x4& b1, f32x4& b2, f32x4& b3,
                    f32x4& b4, f32x4& b5, f32x4& b6, f32x4& b7) {
  asm volatile(
      "global_load_dwordx4 %0, %16, off sc0 sc1\n\t"
      "global_load_dwordx4 %1, %16, off offset:64 sc0 sc1\n\t"
      "global_load_dwordx4 %2, %16, off offset:128 sc0 sc1\n\t"
      "global_load_dwordx4 %3, %16, off offset:192 sc0 sc1\n\t"
      "global_load_dwordx4 %4, %16, off offset:256 sc0 sc1\n\t"
      "global_load_dwordx4 %5, %16, off offset:320 sc0 sc1\n\t"
      "global_load_dwordx4 %6, %16, off offset:384 sc0 sc1\n\t"
      "global_load_dwordx4 %7, %16, off offset:448 sc0 sc1\n\t"
      "global_load_dwordx4 %8, %17, off sc0 sc1\n\t"
      "global_load_dwordx4 %9, %17, off offset:64 sc0 sc1\n\t"
      "global_load_dwordx4 %10, %17, off offset:128 sc0 sc1\n\t"
      "global_load_dwordx4 %11, %17, off offset:192 sc0 sc1\n\t"
      "global_load_dwordx4 %12, %17, off offset:256 sc0 sc1\n\t"
      "global_load_dwordx4 %13, %17, off offset:320 sc0 sc1\n\t"
      "global_load_dwordx4 %14, %17, off offset:384 sc0 sc1\n\t"
      "global_load_dwordx4 %15, %17, off offset:448 sc0 sc1\n\t"
      "s_waitcnt vmcnt(0)"
      : "=&v"(a0), "=&v"(a1), "=&v"(a2), "=&v"(a3), "=&v"(a4), "=&v"(a5), "=&v"(a6), "=&v"(a7),
        "=&v"(b0), "=&v"(b1), "=&v"(b2), "=&v"(b3), "=&v"(b4), "=&v"(b5), "=&v"(b6), "=&v"(b7)
      : "v"(p0), "v"(p1)
      : "memory");
}
// same, but no trailing waitcnt (issue-only; a later ld_a16_coh's vmcnt(0) covers these)
DEV void ld_a16_coh_nw(const void* p0, const void* p1,
                       f32x4& a0, f32x4& a1, f32x4& a2, f32x4& a3,
                       f32x4& a4, f32x4& a5, f32x4& a6, f32x4& a7,
                       f32x4& b0, f32x4& b1, f32x4& b2, f32x4& b3,
                       f32x4& b4, f32x4& b5, f32x4& b6, f32x4& b7) {
  asm volatile(
      "global_load_dwordx4 %0, %16, off sc0 sc1\n\t"
      "global_load_dwordx4 %1, %16, off offset:64 sc0 sc1\n\t"
      "global_load_dwordx4 %2, %16, off offset:128 sc0 sc1\n\t"
      "global_load_dwordx4 %3, %16, off offset:192 sc0 sc1\n\t"
      "global_load_dwordx4 %4, %16, off offset:256 sc0 sc1\n\t"
      "global_load_dwordx4 %5, %16, off offset:320 sc0 sc1\n\t"
      "global_load_dwordx4 %6, %16, off offset:384 sc0 sc1\n\t"
      "global_load_dwordx4 %7, %16, off offset:448 sc0 sc1\n\t"
      "global_load_dwordx4 %8, %17, off sc0 sc1\n\t"
      "global_load_dwordx4 %9, %17, off offset:64 sc0 sc1\n\t"
      "global_load_dwordx4 %10, %17, off offset:128 sc0 sc1\n\t"
      "global_load_dwordx4 %11, %17, off offset:192 sc0 sc1\n\t"
      "global_load_dwordx4 %12, %17, off offset:256 sc0 sc1\n\t"
      "global_load_dwordx4 %13, %17, off offset:320 sc0 sc1\n\t"
      "global_load_dwordx4 %14, %17, off offset:384 sc0 sc1\n\t"
      "global_load_dwordx4 %15, %17, off offset:448 sc0 sc1"
      : "=&v"(a0), "=&v"(a1), "=&v"(a2), "=&v"(a3), "=&v"(a4), "=&v"(a5), "=&v"(a6), "=&v"(a7),
        "=&v"(b0), "=&v"(b1), "=&v"(b2), "=&v"(b3), "=&v"(b4), "=&v"(b5), "=&v"(b6), "=&v"(b7)
      : "v"(p0), "v"(p1)
      : "memory");
}
DEV f32x4 ld16_coh(const void* p) {
  f32x4 r;
  asm volatile("global_load_dwordx4 %0, %1, off sc0 sc1\n\ts_waitcnt vmcnt(0)"
               : "=&v"(r) : "v"(p) : "memory");
  return r;
}
DEV void ld32_coh(const void* p, f32x4& a, f32x4& b) {
  asm volatile(
      "global_load_dwordx4 %0, %2, off sc0 sc1\n\t"
      "global_load_dwordx4 %1, %2, off offset:16 sc0 sc1\n\t"
      "s_waitcnt vmcnt(0)"
      : "=&v"(a), "=&v"(b) : "v"(p) : "memory");
}
DEV void st32_coh(void* p, unsigned v) {
  asm volatile("global_store_dword %0, %1, off sc0 sc1" ::"v"(p), "v"(v) : "memory");
}
DEV void st8_coh(void* p, unsigned lo, unsigned hi) {
  u32x2 v; v[0] = lo; v[1] = hi;
  asm volatile("global_store_dwordx2 %0, %1, off sc0 sc1" ::"v"(p), "v"(v) : "memory");
}

// ---- store-based flag sync: one 64B line per producer block, wave-vectorized polls ----
DEV unsigned ldflag(const unsigned* p) {
  unsigned r;
  asm volatile("global_load_dword %0, %1, off sc0 sc1\n\ts_waitcnt vmcnt(0)"
               : "=&v"(r) : "v"(p) : "memory");
  return r;
}
DEV void poll128(const unsigned* fl, unsigned tgt) {  // 128 flags, stride 16 u32
  if (tgt == 0) return;
  if (threadIdx.x < 64) {
    const unsigned* p0 = fl + (size_t)threadIdx.x * 16;
    const unsigned* p1 = fl + (size_t)(threadIdx.x + 64) * 16;
    for (;;) {
      unsigned a, b;
      asm volatile(
          "global_load_dword %0, %2, off sc0 sc1\n\t"
          "global_load_dword %1, %3, off sc0 sc1\n\t"
          "s_waitcnt vmcnt(0)"
          : "=&v"(a), "=&v"(b) : "v"(p0), "v"(p1) : "memory");
      if (__all((a >= tgt) && (b >= tgt))) break;
      __builtin_amdgcn_s_sleep(1);
    }
  }
  __syncthreads();
}
DEV void poll32(const unsigned* fl, unsigned tgt) {  // 32 flags
  if (threadIdx.x < 64) {
    const unsigned* p0 = fl + (size_t)(threadIdx.x & 31) * 16;
    for (;;) {
      unsigned a = ldflag(p0);
      if (__all(a >= tgt)) break;
      __builtin_amdgcn_s_sleep(1);
    }
  }
  __syncthreads();
}
DEV void pollAB(const unsigned* f0, unsigned t0, const unsigned* f1, unsigned t1) {
  const bool n0 = t0 > 0, n1 = t1 > 0;
  if ((n0 || n1) && threadIdx.x < 64) {
    const unsigned* q0 = f0 + (size_t)threadIdx.x * 16;
    const unsigned* q1 = f0 + (size_t)(threadIdx.x + 64) * 16;
    const unsigned* q2 = f1 + (size_t)threadIdx.x * 16;
    const unsigned* q3 = f1 + (size_t)(threadIdx.x + 64) * 16;
    for (;;) {
      unsigned a, b, c, d;
      asm volatile(
          "global_load_dword %0, %4, off sc0 sc1\n\t"
          "global_load_dword %1, %5, off sc0 sc1\n\t"
          "global_load_dword %2, %6, off sc0 sc1\n\t"
          "global_load_dword %3, %7, off sc0 sc1\n\t"
          "s_waitcnt vmcnt(0)"
          : "=&v"(a), "=&v"(b), "=&v"(c), "=&v"(d)
          : "v"(q0), "v"(q1), "v"(q2), "v"(q3) : "memory");
      bool ok = true;
      if (n0) ok = ok && (a >= t0) && (b >= t0);
      if (n1) ok = ok && (c >= t1) && (d >= t1);
      if (__all(ok)) break;
      __builtin_amdgcn_s_sleep(1);
    }
  }
  __syncthreads();
}
DEV void setflag(unsigned* f, unsigned v) {  // drain all waves' stores, then publish
  asm volatile("s_waitcnt vmcnt(0)" ::: "memory");
  __syncthreads();
  if (threadIdx.x == 0) st32_coh(f, v);
}

// dims
#define Bn 32
#define Sn 128
#define Td 127
#define En 512
#define Hn 1024
#define G4 4096
#define Vn 32000

// ---------------- f32 -> bf16 convert ----------------
typedef u16 u16x8b __attribute__((ext_vector_type(8)));
__global__ __launch_bounds__(256) void cvt_bf16_kernel(const float* __restrict__ in,
                                                       u16* __restrict__ out, int n8) {
  int gid = blockIdx.x * 256 + threadIdx.x;
  if (gid >= n8) return;
  const float4* ip = (const float4*)in + gid * 2;
  float4 x = ip[0], y = ip[1];
  u16x8b o;
  o[0] = f2bf(x.x); o[1] = f2bf(x.y); o[2] = f2bf(x.z); o[3] = f2bf(x.w);
  o[4] = f2bf(y.x); o[5] = f2bf(y.y); o[6] = f2bf(y.z); o[7] = f2bf(y.w);
  ((u16x8b*)out)[gid] = o;
}

// ---------------- embedding gather ----------------
__global__ __launch_bounds__(256) void gather_embed_kernel(const int* __restrict__ idx, int ldidx,
                                                           const float* __restrict__ embed,
                                                           u16* __restrict__ outA, int nrows) {
  int gid = blockIdx.x * 256 + threadIdx.x;
  int total = nrows * (En / 8);
  if (gid >= total) return;
  int r = gid / (En / 8);
  int ck = gid % (En / 8);
  int tcol = r / Bn, b = r % Bn;
  int tok = idx[b * ldidx + tcol];
  const float4* src = (const float4*)(embed + (size_t)tok * En + ck * 8);
  float4 x = src[0], y = src[1];
  u16x8b o;
  o[0] = f2bf(x.x); o[1] = f2bf(x.y); o[2] = f2bf(x.z); o[3] = f2bf(x.w);
  o[4] = f2bf(y.x); o[5] = f2bf(y.y); o[6] = f2bf(y.z); o[7] = f2bf(y.w);
  *(u16x8b*)(outA + (size_t)r * En + ck * 8) = o;
}

// ---------------- tiled GEMM (128x128, BK=32, global_load_lds) ----------------
// mode0: C row-major f32 (+bias0+bias1). mode1: fc epilogue (out[(b*Td+t)*Vn+n]).
__global__ __launch_bounds__(256) void gemm_tile_kernel(const u16* __restrict__ A, int lda,
                                                        const u16* __restrict__ W, int ldw,
                                                        const float* __restrict__ bias0,
                                                        const float* __restrict__ bias1,
                                                        float* __restrict__ Cout, int ldc,
                                                        int Mtiles, int K, int mode) {
  __shared__ u16 Asb[128 * 32];
  __shared__ u16 Bsb[128 * 32];
  int nwg = gridDim.x;
  int cpx = nwg >> 3;
  int bid = ((int)blockIdx.x & 7) * cpx + ((int)blockIdx.x >> 3);
  int mt = bid % Mtiles, nt = bid / Mtiles;
  int tid = threadIdx.x;
  int wave = tid >> 6, lane = tid & 63;
  int lrow = lane & 15, kgrp = lane >> 4;
  int wr = wave >> 1, wc = wave & 1;
  int e0 = wave * 1024 + lane * 8;
  int r0 = e0 >> 5, c0 = e0 & 31;
  int r1 = r0 + 16;
  const u16* Ab = A + (size_t)(mt * 128) * lda;
  const u16* Wb = W + (size_t)(nt * 128) * ldw;
  u16* AsW = Asb + wave * 1024;
  u16* BsW = Bsb + wave * 1024;
  f32x4 acc[4][4] = {};
  for (int k0 = 0; k0 < K; k0 += 32) {
    gld16(Ab + (size_t)r0 * lda + k0 + c0, AsW);
    gld16(Ab + (size_t)r1 * lda + k0 + c0, AsW + 512);
    gld16(Wb + (size_t)r0 * ldw + k0 + c0, BsW);
    gld16(Wb + (size_t)r1 * ldw + k0 + c0, BsW + 512);
    __syncthreads();
    bf16x8 af[4], bfr[4];
#pragma unroll
    for (int i = 0; i < 4; ++i) af[i] = ldfrag(Asb + (wr * 64 + i * 16 + lrow) * 32 + kgrp * 8);
#pragma unroll
    for (int i = 0; i < 4; ++i) bfr[i] = ldfrag(Bsb + (wc * 64 + i * 16 + lrow) * 32 + kgrp * 8);
#pragma unroll
    for (int i = 0; i < 4; ++i)
#pragma unroll
      for (int j = 0; j < 4; ++j) acc[i][j] = mfma16(af[i], bfr[j], acc[i][j]);
    __syncthreads();
  }
  if (mode == 0) {
#pragma unroll
    for (int i = 0; i < 4; ++i) {
      int m = mt * 128 + wr * 64 + i * 16 + kgrp * 4;
#pragma unroll
      for (int j = 0; j < 4; ++j) {
        int n = nt * 128 + wc * 64 + j * 16 + lrow;
        float bb = (bias0 ? bias0[n] : 0.f) + (bias1 ? bias1[n] : 0.f);
#pragma unroll
        for (int r = 0; r < 4; ++r) Cout[(size_t)(m + r) * ldc + n] = acc[i][j][r] + bb;
      }
    }
  } else {
#pragma unroll
    for (int i = 0; i < 4; ++i) {
      int m = mt * 128 + wr * 64 + i * 16 + kgrp * 4;
#pragma unroll
      for (int j = 0; j < 4; ++j) {
        int n = nt * 128 + wc * 64 + j * 16 + lrow;
        float bb = bias0[n];
#pragma unroll
        for (int r = 0; r < 4; ++r) {
          int mm = m + r;
          if (mm < Td * Bn) {
            int tt = mm >> 5, b = mm & 31;
            Cout[((size_t)b * Td + tt) * Vn + n] = acc[i][j][r] + bb;
          }
        }
      }
    }
  }
}

// ---------------- persistent building blocks ----------------
DEV void mm8b(const u16* __restrict__ A0, const char* __restrict__ Wl, int pitchB,
              int kByteBase, int lane, f32x4 acc[2][2]) {
  const int lrow = lane & 15, kgrp = lane >> 4;
  const char* wr0 = Wl + (size_t)lrow * pitchB;
  const char* wr1 = wr0 + (size_t)16 * pitchB;
  const int sw = (lrow & 7) << 4;
  f32x4 s0, s1, s2, s3, s4, s5, s6, s7, u0, u1, u2, u3, u4, u5, u6, u7;
  ld_a16_coh(A0 + (size_t)lrow * 1024 + kgrp * 8, A0 + (size_t)(16 + lrow) * 1024 + kgrp * 8,
             s0, s1, s2, s3, s4, s5, s6, s7, u0, u1, u2, u3, u4, u5, u6, u7);
#define KS(T, U, J, KB)                                                \
  {                                                                    \
    bf16x8 a = asbf(T);                                                \
    int kb = (KB) + (J) * 64 + kgrp * 16;                              \
    bf16x8 w0 = *(const bf16x8*)(wr0 + (size_t)(kb ^ sw));             \
    bf16x8 w1 = *(const bf16x8*)(wr1 + (size_t)(kb ^ sw));             \
    acc[0][0] = mfma16(a, w0, acc[0][0]);                              \
    acc[0][1] = mfma16(a, w1, acc[0][1]);                              \
    bf16x8 cc = asbf(U);                                               \
    acc[1][0] = mfma16(cc, w0, acc[1][0]);                             \
    acc[1][1] = mfma16(cc, w1, acc[1][1]);                             \
  }
  KS(s0, u0, 0, kByteBase) KS(s1, u1, 1, kByteBase) KS(s2, u2, 2, kByteBase)
  KS(s3, u3, 3, kByteBase) KS(s4, u4, 4, kByteBase) KS(s5, u5, 5, kByteBase)
  KS(s6, u6, 6, kByteBase) KS(s7, u7, 7, kByteBase)
}

// paired variant: covers 512 K-elements (two 256-elem batches) with ONE vmcnt wait.
DEV void mm8b_pair(const u16* __restrict__ A0, const char* __restrict__ Wl, int pitchB,
                   int kByteBase, int lane, f32x4 acc[2][2]) {
  const int lrow = lane & 15, kgrp = lane >> 4;
  const char* wr0 = Wl + (size_t)lrow * pitchB;
  const char* wr1 = wr0 + (size_t)16 * pitchB;
  const int sw = (lrow & 7) << 4;
  f32x4 s0, s1, s2, s3, s4, s5, s6, s7, u0, u1, u2, u3, u4, u5, u6, u7;
  f32x4 t0, t1, t2, t3, t4, t5, t6, t7, v0, v1, v2, v3, v4, v5, v6, v7;
  ld_a16_coh_nw(A0 + (size_t)lrow * 1024 + kgrp * 8, A0 + (size_t)(16 + lrow) * 1024 + kgrp * 8,
                s0, s1, s2, s3, s4, s5, s6, s7, u0, u1, u2, u3, u4, u5, u6, u7);
  ld_a16_coh(A0 + (size_t)lrow * 1024 + 256 + kgrp * 8,
             A0 + (size_t)(16 + lrow) * 1024 + 256 + kgrp * 8,
             t0, t1, t2, t3, t4, t5, t6, t7, v0, v1, v2, v3, v4, v5, v6, v7);
  __builtin_amdgcn_sched_barrier(0);  // rule #18: keep MFMAs below the vmcnt(0)
  KS(s0, u0, 0, kByteBase) KS(s1, u1, 1, kByteBase) KS(s2, u2, 2, kByteBase)
  KS(s3, u3, 3, kByteBase) KS(s4, u4, 4, kByteBase) KS(s5, u5, 5, kByteBase)
  KS(s6, u6, 6, kByteBase) KS(s7, u7, 7, kByteBase)
  KS(t0, v0, 0, kByteBase + 512) KS(t1, v1, 1, kByteBase + 512) KS(t2, v2, 2, kByteBase + 512)
  KS(t3, v3, 3, kByteBase + 512) KS(t4, v4, 4, kByteBase + 512) KS(t5, v5, 5, kByteBase + 512)
  KS(t6, v6, 6, kByteBase + 512) KS(t7, v7, 7, kByteBase + 512)
}

DEV void dump_acc(float* red, f32x4 acc[2][2], int wave, int lane) {
  int lrow = lane & 15, kgrp = lane >> 4;
#pragma unroll
  for (int m = 0; m < 2; ++m)
#pragma unroll
    for (int n = 0; n < 2; ++n)
#pragma unroll
      for (int r = 0; r < 4; ++r)
        red[((((wave * 2 + m) * 2 + n) * 16) + kgrp * 4 + r) * 16 + lrow] = acc[m][n][r];
}
DEV float rsum(const float* red, int m, int n, int rw, int l) {
  float s = 0.f;
#pragma unroll
  for (int w = 0; w < 4; ++w) s += red[((((w * 2 + m) * 2 + n) * 16) + rw) * 16 + l];
  return s;
}
DEV float lstm_apply(const float gs[4], float* c_reg) {
  float ig = sigf(gs[0]), fg = sigf(gs[1]), gg = tanhf(gs[2]), og = sigf(gs[3]);
  float cn = fg * (*c_reg) + ig * gg;
  *c_reg = cn;
  return og * tanhf(cn);
}

// ---------------- persistent encoder (round-13 + premix prefetch before poll) ----------------
__global__ __launch_bounds__(256, 1) void enc_persist9(
    const float* __restrict__ premix, const u16* __restrict__ Whh0, const u16* __restrict__ Wih1,
    const u16* __restrict__ Whh1, const float* __restrict__ bih1, const float* __restrict__ bhh1,
    u16* __restrict__ h0ring, u16* __restrict__ h1ring, float* __restrict__ c1_out,
    u16* __restrict__ enc_b, unsigned* __restrict__ f0, unsigned* __restrict__ f1) {
  extern __shared__ char lds[];
  float* red = (float*)(lds + 131072);
  const int tid = threadIdx.x, wave = tid >> 6, lane = tid & 63;
  const int blk = blockIdx.x;
  const bool l1 = blk >= 128;
  const int base = (blk & 127) * 8;
  if (!l1) {
    for (int i = tid; i < 4096; i += 256) {
      int c = i >> 7;
      int kb = (i & 127) << 4;
      int row = (c >> 3) * Hn + base + (c & 7);
      f32x4 v = *(const f32x4*)(Whh0 + (size_t)row * Hn + (kb >> 1));
      *(f32x4*)(lds + c * 2048 + (kb ^ ((c & 7) << 4))) = v;
    }
  } else {
    for (int i = tid; i < 8192; i += 256) {
      int c = i >> 8;
      int kb = (i & 255) << 4;
      int row = (c >> 3) * Hn + base + (c & 7);
      const u16* src = (kb < 2048) ? (Wih1 + (size_t)row * Hn + (kb >> 1))
                                   : (Whh1 + (size_t)row * Hn + ((kb - 2048) >> 1));
      f32x4 v = *(const f32x4*)src;
      *(f32x4*)(lds + c * 4096 + (kb ^ ((c & 7) << 4))) = v;
    }
  }
  const int b_ = tid >> 3, hc = tid & 7;
  const int m = b_ >> 4, rw = b_ & 15;
  const size_t off = (size_t)b_ * Hn + base + hc;
  float c_reg = 0.f;
  __syncthreads();
  if (!l1) {
    for (int i = 0; i < Sn; ++i) {
      // premix[i] is input-only: prefetch BEFORE the poll (latency hides under wait)
      const float* pmr = premix + (size_t)i * (Bn * G4) + (size_t)b_ * G4 + base + hc;
      float pmv[4];
#pragma unroll
      for (int g = 0; g < 4; ++g) pmv[g] = pmr[(size_t)g * Hn];
      pollAB(f0, (unsigned)i, f1, (i >= 3) ? (unsigned)(i - 2) : 0u);
      const u16* hin = h0ring + (size_t)(i & 3) * (Bn * Hn);
      f32x4 acc[2][2] = {};
      mm8b(hin + wave * 256, lds, 2048, wave * 512, lane, acc);
      dump_acc(red, acc, wave, lane);
      __syncthreads();
      float gs[4];
#pragma unroll
      for (int g = 0; g < 4; ++g) {
        int c = g * 8 + hc;
        gs[g] = rsum(red, m, c >> 4, rw, c & 15) + pmv[g];
      }
      float hn = lstm_apply(gs, &c_reg);
      u16 mine = f2bf(hn);
      unsigned nb = (unsigned)(u16)__shfl_xor((int)mine, 1);
      if (!(tid & 1))
        st32_coh(h0ring + (size_t)((i + 1) & 3) * (Bn * Hn) + off,
                 ((unsigned)mine) | (nb << 16));
      setflag(f0 + blk * 16, (unsigned)(i + 1));
    }
  } else {
    float badd[4];
#pragma unroll
    for (int g = 0; g < 4; ++g) badd[g] = bih1[g * Hn + base + hc] + bhh1[g * Hn + base + hc];
    for (int j = 0; j < Sn; ++j) {
      pollAB(f0, (unsigned)(j + 1), f1, (unsigned)j);
      const u16* h0r = h0ring + (size_t)((j + 1) & 3) * (Bn * Hn);  // h0(j)
      const u16* h1r = h1ring + (size_t)(j & 1) * (Bn * Hn);        // h1(j-1)
      const u16* srcp = (wave < 2) ? h0r : h1r;
      int ko = (wave & 1) * 512;
      f32x4 acc[2][2] = {};
      mm8b_pair(srcp + ko, lds, 4096, wave * 1024, lane, acc);
      dump_acc(red, acc, wave, lane);
      __syncthreads();
      float gs[4];
#pragma unroll
      for (int g = 0; g < 4; ++g) {
        int c = g * 8 + hc;
        gs[g] = rsum(red, m, c >> 4, rw, c & 15) + badd[g];
      }
      float hn = lstm_apply(gs, &c_reg);
      u16 mine = f2bf(hn);
      unsigned nb = (unsigned)(u16)__shfl_xor((int)mine, 1);
      unsigned packed = ((unsigned)mine) | (nb << 16);
      if (!(tid & 1)) {
        st32_coh(h1ring + (size_t)((j + 1) & 1) * (Bn * Hn) + off, packed);
        *(unsigned*)(enc_b + (size_t)j * (Bn * Hn) + off) = packed;  // plain: later kernels
      }
      if (j == Sn - 1) c1_out[off] = c_reg;
      setflag(f1 + (blk - 128) * 16, (unsigned)(j + 1));
    }
  }
}

// ---------------- persistent decoder v12: round-13 + premix prefetch before poll ----------------
// blk<128 gate: prefetch premix -> poll fg>=t -> GEMM1(Whh@h) -> poll fa>=t+1 ->
//   GEMM2(Wctx@ctx) -> LSTM -> publish h(t+1).
// blk in [128,160) scorer b: poll fg>=t -> shfl-free scores -> softmax -> wsum -> fa[b]=t+1.
__global__ __launch_bounds__(256, 1) void dec_persist12(
    const float* __restrict__ premix, const u16* __restrict__ Wctx, const u16* __restrict__ Whh,
    const float* __restrict__ c_init, u16* __restrict__ hbuf /*2 slots*/,
    const u16* __restrict__ enc_b, u16* __restrict__ ctxb, u16* __restrict__ hs_dec,
    unsigned* __restrict__ fg, unsigned* __restrict__ fa) {
  extern __shared__ char lds[];
  const int tid = threadIdx.x, wave = tid >> 6, lane = tid & 63;
  const int blk = blockIdx.x;
  if (blk < 128) {
    float* red = (float*)(lds + 131072);  // 16 KB; total 147456 B dynamic LDS
    const int cg = blk, base = cg * 8;
    // stage Whh (bytes 0..2047 per col) + Wctx (2048..4095), XOR-swizzled
    for (int i = tid; i < 8192; i += 256) {
      int c = i >> 8;
      int kb = (i & 255) << 4;
      int row = (c >> 3) * Hn + base + (c & 7);
      const u16* src = (kb < 2048) ? (Whh + (size_t)row * Hn + (kb >> 1))
                                   : (Wctx + (size_t)row * 1536 + ((kb - 2048) >> 1));
      f32x4 v = *(const f32x4*)src;
      *(f32x4*)(lds + c * 4096 + (kb ^ ((c & 7) << 4))) = v;
    }
    const int b_ = tid >> 3, hc = tid & 7;
    const int m = b_ >> 4, rw = b_ & 15;
    const size_t off = (size_t)b_ * Hn + base + hc;
    float c_reg = c_init[off];
    __syncthreads();
    for (int t = 0; t < Td; ++t) {
      // premix[t] is input-only: prefetch BEFORE the poll
      const float* pmr = premix + (size_t)t * (Bn * G4) + (size_t)b_ * G4 + base + hc;
      float pmv[4];
#pragma unroll
      for (int g = 0; g < 4; ++g) pmv[g] = pmr[(size_t)g * Hn];
      poll128(fg, (unsigned)t);  // h(t) ready (t=0: preloaded h_last)
      f32x4 acc[2][2] = {};
      // GEMM1: Whh @ h(t)  (overlaps the scorer phase)
      mm8b(hbuf + (size_t)(t & 1) * (Bn * Hn) + wave * 256, lds, 4096, wave * 512, lane, acc);
      // wait ctx(t)
      poll32(fa, (unsigned)(t + 1));
      // GEMM2: Wctx @ ctx(t), same accumulator
      mm8b(ctxb + wave * 256, lds, 4096, 2048 + wave * 512, lane, acc);
      dump_acc(red, acc, wave, lane);
      __syncthreads();
      float gs[4];
#pragma unroll
      for (int g = 0; g < 4; ++g) {
        int c = g * 8 + hc;
        gs[g] = rsum(red, m, c >> 4, rw, c & 15) + pmv[g];
      }
      float hn = lstm_apply(gs, &c_reg);
      u16 mine = f2bf(hn);
      unsigned nb = (unsigned)(u16)__shfl_xor((int)mine, 1);
      unsigned packed = ((unsigned)mine) | (nb << 16);
      if (!(tid & 1)) {
        st32_coh(hbuf + (size_t)((t + 1) & 1) * (Bn * Hn) + off, packed);
        *(unsigned*)(hs_dec + (size_t)t * (Bn * Hn) + off) = packed;  // plain: fc kernel
      }
      setflag(fg + cg * 16, (unsigned)(t + 1));
    }
  } else {
    // ---------------- scorer for batch b: shuffle-free pass 1 (round-13 proven) -----------
    float* scpart = (float*)lds;                                  // [128][65] = 33280 B
    float* scl = (float*)(lds + 33280);                           // 512 B
    float* wsm = (float*)(lds + 33792);                           // 512 B
    float(*cpart)[16][64] = (float(*)[16][64])(lds + 34304);      // 16 KB
    const int b = blk - 128;
    for (int t = 0; t < Td; ++t) {
      poll128(fg, (unsigned)t);
      const u16* hb = hbuf + (size_t)(t & 1) * (Bn * Hn) + (size_t)b * Hn;
      // each lane loads its own 32B of h (coherent), no LDS bounce
      float hf[16];
      {
        union { f32x4 f[2]; u16 u[16]; } U;
        ld32_coh(hb + lane * 16, U.f[0], U.f[1]);
#pragma unroll
        for (int k2 = 0; k2 < 16; ++k2) hf[k2] = bf2f(U.u[k2]);
      }
      // pass 1: per-lane partial dots -> LDS (no cross-lane ops)
#pragma unroll 4
      for (int i = 0; i < 32; ++i) {
        int s = wave * 32 + i;
        const u16* er = enc_b + ((size_t)s * Bn + b) * Hn + lane * 16;
        u16x8 e0 = *(const u16x8*)er;
        u16x8 e1 = *(const u16x8*)(er + 8);
        float p2 = 0.f;
#pragma unroll
        for (int k2 = 0; k2 < 8; ++k2) p2 += bf2f(e0[k2]) * hf[k2] + bf2f(e1[k2]) * hf[8 + k2];
        scpart[s * 65 + lane] = p2;
      }
      __syncthreads();
      // reduce: 2 threads per score, 32 sequential adds each, combine via 1 shfl
      {
        int s2 = tid >> 1, half = tid & 1;
        const float* pp = scpart + s2 * 65 + half * 32;
        float p = 0.f;
#pragma unroll
        for (int j = 0; j < 32; ++j) p += pp[j];
        p += __shfl_xor(p, 1);
        if (half == 0) scl[s2] = p;
      }
      __syncthreads();
      if (wave == 0) {
        float sa = scl[lane], sb = scl[64 + lane];
        float mx = fmaxf(sa, sb);
#pragma unroll
        for (int o2 = 32; o2; o2 >>= 1) mx = fmaxf(mx, __shfl_xor(mx, o2));
        float ea = __expf(sa - mx), eb = __expf(sb - mx);
        float ss = ea + eb;
#pragma unroll
        for (int o2 = 32; o2; o2 >>= 1) ss += __shfl_xor(ss, o2);
        float inv = 1.0f / ss;
        wsm[lane] = ea * inv;
        wsm[64 + lane] = eb * inv;
      }
      __syncthreads();
      // pass 2: weighted accumulation (per-lane 16 cols, no cross-lane)
      float a0[16];
#pragma unroll
      for (int q = 0; q < 16; ++q) a0[q] = 0.f;
      for (int i = 0; i < 32; ++i) {
        int s = wave * 32 + i;
        float w = wsm[s];
        const u16* er = enc_b + ((size_t)s * Bn + b) * Hn + lane * 16;
        u16x8 e0 = *(const u16x8*)er;
        u16x8 e1 = *(const u16x8*)(er + 8);
#pragma unroll
        for (int q = 0; q < 8; ++q) {
          a0[q] += w * bf2f(e0[q]);
          a0[8 + q] += w * bf2f(e1[q]);
        }
      }
#pragma unroll
      for (int q = 0; q < 16; ++q) cpart[wave][q][lane] = a0[q];
      __syncthreads();
      {
        unsigned pk[2];
#pragma unroll
        for (int h2 = 0; h2 < 2; ++h2) {
          float v0 = 0.f, v1 = 0.f;
          int j0 = tid * 4 + h2 * 2;
#pragma unroll
          for (int w2 = 0; w2 < 4; ++w2) {
            v0 += cpart[w2][j0 & 15][j0 >> 4];
            v1 += cpart[w2][(j0 + 1) & 15][(j0 + 1) >> 4];
          }
          pk[h2] = (unsigned)f2bf(v0) | ((unsigned)f2bf(v1) << 16);
        }
        st8_coh(ctxb + (size_t)b * Hn + tid * 4, pk[0], pk[1]);
      }
      setflag(fa + b * 16, (unsigned)(t + 1));
    }
  }
}

// ---------------- host ----------------
extern "C" void kernel_launch(void* const* d_in, const int* in_sizes, int n_in,
                              void* d_out, int out_size, void* d_ws, size_t ws_size,
                              hipStream_t stream) {
  const int* src = (const int*)d_in[0];
  const int* tgt = (const int*)d_in[1];
  const float* embed = (const float*)d_in[2];
  const float* Wih0 = (const float*)d_in[3];
  const float* Whh0 = (const float*)d_in[4];
  const float* bih0 = (const float*)d_in[5];
  const float* bhh0 = (const float*)d_in[6];
  const float* Wih1 = (const float*)d_in[7];
  const float* Whh1 = (const float*)d_in[8];
  const float* bih1 = (const float*)d_in[9];
  const float* bhh1 = (const float*)d_in[10];
  const float* dWih = (const float*)d_in[11];
  const float* dWhh = (const float*)d_in[12];
  const float* dbih = (const float*)d_in[13];
  const float* dbhh = (const float*)d_in[14];
  const float* fcW = (const float*)d_in[15];
  const float* fcb = (const float*)d_in[16];
  float* out = (float*)d_out;

  (void)hipFuncSetAttribute((const void*)enc_persist9,
                            hipFuncAttributeMaxDynamicSharedMemorySize, 147456);
  (void)hipFuncSetAttribute((const void*)dec_persist12,
                            hipFuncAttributeMaxDynamicSharedMemorySize, 147456);

  char* p = (char*)d_ws;
  auto alloc = [&](size_t bytes) {
    void* r = p;
    p += (bytes + 255) & ~(size_t)255;
    return r;
  };
  u16* Wih0_b = (u16*)alloc((size_t)G4 * En * 2);
  u16* Whh0_b = (u16*)alloc((size_t)G4 * Hn * 2);
  u16* Wih1_b = (u16*)alloc((size_t)G4 * Hn * 2);
  u16* Whh1_b = (u16*)alloc((size_t)G4 * Hn * 2);
  u16* dWih_b = (u16*)alloc((size_t)G4 * 1536 * 2);
  u16* dWhh_b = (u16*)alloc((size_t)G4 * Hn * 2);
  u16* fcW_b = (u16*)alloc((size_t)Vn * Hn * 2);
  u16* embA = (u16*)alloc((size_t)4096 * En * 2);
  float* premix = (float*)alloc((size_t)4096 * G4 * 4);  // reused: enc l0, then decoder
  u16* enc_b = (u16*)alloc((size_t)Sn * Bn * Hn * 2);
  u16* hs_dec = (u16*)alloc((size_t)4096 * Hn * 2);
  u16* h0ring = (u16*)alloc((size_t)4 * Bn * Hn * 2);
  u16* h1ring = (u16*)alloc((size_t)2 * Bn * Hn * 2);
  float* c1g = (float*)alloc((size_t)Bn * Hn * 4);
  u16* ctx_b = (u16*)alloc((size_t)Bn * Hn * 2);
  unsigned* counters = (unsigned*)alloc(65536);
  unsigned* flagsE0 = counters;          // 128 x 16 u32
  unsigned* flagsE1 = counters + 2048;
  unsigned* flagsDg = counters + 4096;   // 128 x 16 u32
  unsigned* flagsDa = counters + 6144;   // 32 x 16 u32

  auto cvt = [&](const float* in, u16* o, size_t n) {
    int n8 = (int)(n / 8);
    cvt_bf16_kernel<<<(n8 + 255) / 256, 256, 0, stream>>>(in, o, n8);
  };
  cvt(Wih0, Wih0_b, (size_t)G4 * En);
  cvt(Whh0, Whh0_b, (size_t)G4 * Hn);
  cvt(Wih1, Wih1_b, (size_t)G4 * Hn);
  cvt(Whh1, Whh1_b, (size_t)G4 * Hn);
  cvt(dWih, dWih_b, (size_t)G4 * 1536);
  cvt(dWhh, dWhh_b, (size_t)G4 * Hn);
  cvt(fcW, fcW_b, (size_t)Vn * Hn);

  // encoder premix (layer0 input projection for all t)
  {
    int total = 4096 * (En / 8);
    gather_embed_kernel<<<(total + 255) / 256, 256, 0, stream>>>(src, Sn, embed, embA, Sn * Bn);
    gemm_tile_kernel<<<32 * 32, 256, 0, stream>>>(embA, En, Wih0_b, En, bih0, bhh0, premix, G4,
                                                  32, En, 0);
  }
  (void)hipMemsetAsync(h0ring, 0, (size_t)4 * Bn * Hn * 2, stream);
  (void)hipMemsetAsync(h1ring, 0, (size_t)2 * Bn * Hn * 2, stream);
  (void)hipMemsetAsync(counters, 0, 65536, stream);
  (void)hipMemsetAsync(hs_dec + (size_t)(Td * Bn) * Hn, 0, (size_t)(4096 - Td * Bn) * Hn * 2,
                       stream);

  enc_persist9<<<256, 256, 147456, stream>>>(premix, Whh0_b, Wih1_b, Whh1_b, bih1, bhh1, h0ring,
                                             h1ring, c1g, enc_b, flagsE0, flagsE1);

  // decoder premix
  {
    int nrows = Td * Bn;
    int total = nrows * (En / 8);
    gather_embed_kernel<<<(total + 255) / 256, 256, 0, stream>>>(tgt, Sn, embed, embA, nrows);
    gemm_tile_kernel<<<32 * 32, 256, 0, stream>>>(embA, En, dWih_b, 1536, dbih, dbhh, premix, G4,
                                                  32, En, 0);
  }

  dec_persist12<<<160, 256, 147456, stream>>>(premix, dWih_b + 512, dWhh_b, c1g,
                                              h1ring /* slot0 = h_last */, enc_b, ctx_b, hs_dec,
                                              flagsDg, flagsDa);

  // batched fc: out = hs_dec @ fc_W^T + fc_b
  gemm_tile_kernel<<<32 * 250, 256, 0, stream>>>(hs_dec, Hn, fcW_b, Hn, fcb, nullptr, out, 0,
                                                 32, Hn, 1);
}